// Round 1
// baseline (1045.360 us; speedup 1.0000x reference)
//
#include <hip/hip_runtime.h>

#define B_ 4
#define S_ 2048
#define H_ 1024
#define NH_ 16
#define HD_ 64
#define FF_ 4096

typedef __attribute__((ext_vector_type(8))) short bfx8;
typedef __attribute__((ext_vector_type(4))) float f32x4;
typedef __attribute__((ext_vector_type(4))) unsigned short us4;

__device__ __forceinline__ unsigned short f2bf(float x) {
  union { float f; unsigned u; } c; c.f = x;
  unsigned r = c.u + 0x7FFFu + ((c.u >> 16) & 1u);
  return (unsigned short)(r >> 16);
}
__device__ __forceinline__ unsigned pack2(float a, float b) {
  return (unsigned)f2bf(a) | ((unsigned)f2bf(b) << 16);
}
__device__ __forceinline__ f32x4 mfma16(bfx8 a, bfx8 b, f32x4 c) {
  return __builtin_amdgcn_mfma_f32_16x16x32_bf16(a, b, c, 0, 0, 0);
}
__device__ __forceinline__ void async16(const unsigned short* g, unsigned short* l) {
  __builtin_amdgcn_global_load_lds(
      (const __attribute__((address_space(1))) unsigned int*)g,
      (__attribute__((address_space(3))) unsigned int*)l, 16, 0, 0);
}
__device__ __forceinline__ float gelu_f(float x) {
  float u = 0.7978845608028654f * (x + 0.044715f * x * x * x);
  float e = __expf(2.f * u);
  float t = 1.f - 2.f / (e + 1.f);
  return 0.5f * x * (1.f + t);
}

// ---------------- fp32 -> bf16 convert (vector of 4) ----------------
__global__ __launch_bounds__(256) void k_cvt(const float* __restrict__ in,
                                             unsigned short* __restrict__ out, int n4) {
  int i = blockIdx.x * 256 + threadIdx.x;
  if (i >= n4) return;
  float4 v = ((const float4*)in)[i];
  us4 o; o.x = f2bf(v.x); o.y = f2bf(v.y); o.z = f2bf(v.z); o.w = f2bf(v.w);
  ((us4*)out)[i] = o;
}

// ---------------- W [K][N] f32 -> WT [N][K] bf16 ----------------
__global__ __launch_bounds__(256) void k_wtrans(const float* __restrict__ W,
                                                unsigned short* __restrict__ WT,
                                                int K, int N) {
  __shared__ float tile[64][65];
  int k0 = blockIdx.x * 64, n0 = blockIdx.y * 64;
  int t = threadIdx.x;
#pragma unroll
  for (int i = 0; i < 16; i++) {
    int li = t + i * 256;
    int kl = li >> 6, nl = li & 63;
    tile[kl][nl] = W[(size_t)(k0 + kl) * N + n0 + nl];
  }
  __syncthreads();
#pragma unroll
  for (int i = 0; i < 16; i++) {
    int li = t + i * 256;
    int nl = li >> 6, kl = li & 63;
    WT[(size_t)(n0 + nl) * K + k0 + kl] = f2bf(tile[kl][nl]);
  }
}

// ---------------- V [B*S][H] bf16 -> VT [B*NH][HD][S] bf16 ----------------
__global__ __launch_bounds__(256) void k_vtrans(const unsigned short* __restrict__ v,
                                                unsigned short* __restrict__ vt) {
  __shared__ unsigned short tile[64][65];
  int s0 = blockIdx.x * 64;
  int bh = blockIdx.y;
  int b = bh >> 4, h = bh & 15;
  int t = threadIdx.x;
#pragma unroll
  for (int i = 0; i < 16; i++) {
    int li = t + i * 256;
    int sl = li >> 6, dl = li & 63;
    tile[sl][dl] = v[(size_t)(b * S_ + s0 + sl) * H_ + h * HD_ + dl];
  }
  __syncthreads();
#pragma unroll
  for (int i = 0; i < 16; i++) {
    int li = t + i * 256;
    int dl = li >> 6, sl = li & 63;
    vt[((size_t)bh * HD_ + dl) * S_ + s0 + sl] = tile[sl][dl];
  }
}

// ---------------- GEMM: C = A[M][K] @ BT[N][K]^T + bias ----------------
// EPI: 0 = bf16 out, 1 = bf16 out * 0.125 (Q prescale), 2 = f32 out, 3 = bf16 gelu
template <int EPI>
__global__ __launch_bounds__(256) void k_gemm_bt(
    const unsigned short* __restrict__ A, const unsigned short* __restrict__ BT,
    const float* __restrict__ bias, float* __restrict__ Cf,
    unsigned short* __restrict__ Cb, int M, int N, int K) {
  __shared__ unsigned short As[128 * 32];
  __shared__ unsigned short Bs[128 * 32];
  const int tid = threadIdx.x;
  const int bx = blockIdx.x, by = blockIdx.y;
  const int wid = tid >> 6, lane = tid & 63;
  const int wr = wid >> 1, wc = wid & 1;
  const int lrow = lane & 15, lk = lane >> 4;

  f32x4 acc[4][4] = {};

  const int arow = tid >> 2, aseg = tid & 3;
  const unsigned short* gA = A + (size_t)(by * 128 + arow) * K + aseg * 8;
  const unsigned short* gB = BT + (size_t)(bx * 128 + arow) * K + aseg * 8;
  unsigned short* lA0 = &As[(tid & ~63) * 8];
  unsigned short* lA1 = lA0 + 2048;
  unsigned short* lB0 = &Bs[(tid & ~63) * 8];
  unsigned short* lB1 = lB0 + 2048;

  for (int k0 = 0; k0 < K; k0 += 32) {
    async16(gA + k0, lA0);
    async16(gA + (size_t)64 * K + k0, lA1);
    async16(gB + k0, lB0);
    async16(gB + (size_t)64 * K + k0, lB1);
    __syncthreads();
    bfx8 af[4], bf[4];
#pragma unroll
    for (int m = 0; m < 4; m++)
      af[m] = *(const bfx8*)&As[(wr * 64 + m * 16 + lrow) * 32 + lk * 8];
#pragma unroll
    for (int n = 0; n < 4; n++)
      bf[n] = *(const bfx8*)&Bs[(wc * 64 + n * 16 + lrow) * 32 + lk * 8];
#pragma unroll
    for (int m = 0; m < 4; m++)
#pragma unroll
      for (int n = 0; n < 4; n++)
        acc[m][n] = mfma16(af[m], bf[n], acc[m][n]);
    __syncthreads();
  }

#pragma unroll
  for (int n = 0; n < 4; n++) {
    const int gcol = bx * 128 + wc * 64 + n * 16 + lrow;
    const float bz = bias[gcol];
#pragma unroll
    for (int m = 0; m < 4; m++) {
      const int gr = by * 128 + wr * 64 + m * 16 + lk * 4;
#pragma unroll
      for (int r = 0; r < 4; r++) {
        float v = acc[m][n][r] + bz;
        if (EPI == 1) v *= 0.125f;
        if (EPI == 3) v = gelu_f(v);
        size_t idx = (size_t)(gr + r) * N + gcol;
        if (EPI == 2) Cf[idx] = v;
        else Cb[idx] = f2bf(v);
      }
    }
  }
}

// ---------------- fused flash attention ----------------
// q pre-scaled by 1/8. grid: (S/64, B*NH), 256 thr = 4 waves, wave = 16 q rows.
__global__ __launch_bounds__(256) void k_attn(
    const unsigned short* __restrict__ q, const unsigned short* __restrict__ k,
    const unsigned short* __restrict__ vt, const float* __restrict__ mask,
    unsigned short* __restrict__ ctx) {
  __shared__ unsigned short P[4][16 * 40];  // per-wave P, row stride 40 (pad)
  const int qb = blockIdx.x, bh = blockIdx.y;
  const int b = bh >> 4, h = bh & 15;
  const int tid = threadIdx.x, wid = tid >> 6, lane = tid & 63;
  const int lq = lane & 15, lg = lane >> 4;
  const int q0 = qb * 64 + wid * 16;

  const size_t qrow = ((size_t)b * S_ + q0 + lq) * H_ + h * HD_;
  const bfx8 qf0 = *(const bfx8*)&q[qrow + lg * 8];
  const bfx8 qf1 = *(const bfx8*)&q[qrow + 32 + lg * 8];

  float m_run = -1e30f, l_run = 0.f;
  f32x4 o[4] = {};
  unsigned short* Pw = &P[wid][0];
  unsigned* Pw32 = (unsigned*)Pw;
  const size_t vbase = (size_t)bh * HD_ * S_;
  const float* mrow = mask + (size_t)b * S_;

  for (int kb = 0; kb < S_; kb += 32) {
    // S^T tiles: D[key][q] = K-tile @ Q^T
    const size_t kr0 = ((size_t)b * S_ + kb + lq) * H_ + h * HD_;
    const bfx8 k00 = *(const bfx8*)&k[kr0 + lg * 8];
    const bfx8 k01 = *(const bfx8*)&k[kr0 + 32 + lg * 8];
    const bfx8 k10 = *(const bfx8*)&k[kr0 + (size_t)16 * H_ + lg * 8];
    const bfx8 k11 = *(const bfx8*)&k[kr0 + (size_t)16 * H_ + 32 + lg * 8];
    f32x4 s0 = {}, s1 = {};
    s0 = mfma16(k00, qf0, s0);
    s0 = mfma16(k01, qf1, s0);
    s1 = mfma16(k10, qf0, s1);
    s1 = mfma16(k11, qf1, s1);
    const f32x4 mk0 = *(const f32x4*)&mrow[kb + lg * 4];
    const f32x4 mk1 = *(const f32x4*)&mrow[kb + 16 + lg * 4];
    s0 += mk0;
    s1 += mk1;
    // online softmax (row stats per q = lq; keys live across lg groups)
    float mx = fmaxf(fmaxf(fmaxf(s0[0], s0[1]), fmaxf(s0[2], s0[3])),
                     fmaxf(fmaxf(s1[0], s1[1]), fmaxf(s1[2], s1[3])));
    mx = fmaxf(mx, __shfl_xor(mx, 16));
    mx = fmaxf(mx, __shfl_xor(mx, 32));
    const float m_new = fmaxf(m_run, mx);
    const float scale = __expf(m_run - m_new);
    float p0 = __expf(s0[0] - m_new), p1 = __expf(s0[1] - m_new);
    float p2 = __expf(s0[2] - m_new), p3 = __expf(s0[3] - m_new);
    float p4 = __expf(s1[0] - m_new), p5 = __expf(s1[1] - m_new);
    float p6 = __expf(s1[2] - m_new), p7 = __expf(s1[3] - m_new);
    float ps = ((p0 + p1) + (p2 + p3)) + ((p4 + p5) + (p6 + p7));
    ps += __shfl_xor(ps, 16);
    ps += __shfl_xor(ps, 32);
    l_run = l_run * scale + ps;
    m_run = m_new;
#pragma unroll
    for (int td = 0; td < 4; td++) o[td] *= scale;
    // P[q][key] bf16 into LDS (row stride 40 elems)
    const int pd = lq * 20 + lg * 2;
    Pw32[pd] = pack2(p0, p1);
    Pw32[pd + 1] = pack2(p2, p3);
    Pw32[pd + 8] = pack2(p4, p5);
    Pw32[pd + 9] = pack2(p6, p7);
    asm volatile("s_waitcnt lgkmcnt(0)" ::: "memory");
    __builtin_amdgcn_sched_barrier(0);
    // PV: O^T += V^T-tile @ P^T
    const bfx8 pb = *(const bfx8*)&Pw[lq * 40 + lg * 8];
#pragma unroll
    for (int td = 0; td < 4; td++) {
      const bfx8 vf = *(const bfx8*)&vt[vbase + (size_t)(td * 16 + lq) * S_ + kb + lg * 8];
      o[td] = mfma16(vf, pb, o[td]);
    }
  }
  const float inv = 1.f / l_run;
  unsigned short* crow = ctx + ((size_t)b * S_ + q0 + lq) * H_ + h * HD_;
#pragma unroll
  for (int td = 0; td < 4; td++) {
    float v0 = o[td][0] * inv, v1 = o[td][1] * inv;
    float v2 = o[td][2] * inv, v3 = o[td][3] * inv;
    *(unsigned*)&crow[td * 16 + lg * 4] = pack2(v0, v1);
    *(unsigned*)&crow[td * 16 + lg * 4 + 2] = pack2(v2, v3);
  }
}

// ---------------- residual + layernorm ----------------
template <int WB>
__global__ __launch_bounds__(256) void k_ln(
    const float* __restrict__ xa, const float* __restrict__ xb,
    const float* __restrict__ g, const float* __restrict__ bt,
    float* __restrict__ outf, unsigned short* __restrict__ outb) {
  const int row = blockIdx.x;
  const int t = threadIdx.x;
  const size_t off = (size_t)row * H_ + t * 4;
  float4 va = *(const float4*)(xa + off);
  float4 vb = *(const float4*)(xb + off);
  float v0 = va.x + vb.x, v1 = va.y + vb.y, v2 = va.z + vb.z, v3 = va.w + vb.w;
  float s = (v0 + v1) + (v2 + v3);
#pragma unroll
  for (int d = 1; d < 64; d <<= 1) s += __shfl_xor(s, d);
  __shared__ float red1[4], red2[4];
  const int wid = t >> 6, lane = t & 63;
  if (lane == 0) red1[wid] = s;
  __syncthreads();
  const float mean = (red1[0] + red1[1] + red1[2] + red1[3]) * (1.f / H_);
  float d0 = v0 - mean, d1 = v1 - mean, d2 = v2 - mean, d3 = v3 - mean;
  float ss = (d0 * d0 + d1 * d1) + (d2 * d2 + d3 * d3);
#pragma unroll
  for (int d = 1; d < 64; d <<= 1) ss += __shfl_xor(ss, d);
  if (lane == 0) red2[wid] = ss;
  __syncthreads();
  const float var = (red2[0] + red2[1] + red2[2] + red2[3]) * (1.f / H_);
  const float rstd = rsqrtf(var + 1e-12f);
  const float4 gv = *(const float4*)(g + t * 4);
  const float4 bv = *(const float4*)(bt + t * 4);
  float y0 = d0 * rstd * gv.x + bv.x;
  float y1 = d1 * rstd * gv.y + bv.y;
  float y2 = d2 * rstd * gv.z + bv.z;
  float y3 = d3 * rstd * gv.w + bv.w;
  float4 yo; yo.x = y0; yo.y = y1; yo.z = y2; yo.w = y3;
  *(float4*)(outf + off) = yo;
  if (WB) {
    us4 ob; ob.x = f2bf(y0); ob.y = f2bf(y1); ob.z = f2bf(y2); ob.w = f2bf(y3);
    *(us4*)(outb + off) = ob;
  }
}

extern "C" void kernel_launch(void* const* d_in, const int* in_sizes, int n_in,
                              void* d_out, int out_size, void* d_ws, size_t ws_size,
                              hipStream_t stream) {
  const float* x    = (const float*)d_in[0];
  const float* mask = (const float*)d_in[1];
  const float* Wq = (const float*)d_in[2];
  const float* bq = (const float*)d_in[3];
  const float* Wk = (const float*)d_in[4];
  const float* bk = (const float*)d_in[5];
  const float* Wv = (const float*)d_in[6];
  const float* bv = (const float*)d_in[7];
  const float* Wo = (const float*)d_in[8];
  const float* bo = (const float*)d_in[9];
  const float* g1  = (const float*)d_in[10];
  const float* be1 = (const float*)d_in[11];
  const float* W1 = (const float*)d_in[12];
  const float* b1 = (const float*)d_in[13];
  const float* W2 = (const float*)d_in[14];
  const float* b2 = (const float*)d_in[15];
  const float* g2  = (const float*)d_in[16];
  const float* be2 = (const float*)d_in[17];
  float* out = (float*)d_out;

  char* ws = (char*)d_ws;
  unsigned short* WT   = (unsigned short*)(ws + 0);           // 8 MiB (max 4096x1024 bf16)
  unsigned short* XBF  = (unsigned short*)(ws + 8388608);     // 16 MiB, later VT
  unsigned short* QBF  = (unsigned short*)(ws + 25165824);    // 16 MiB
  unsigned short* KBF  = (unsigned short*)(ws + 41943040);    // 16 MiB
  unsigned short* VBF  = (unsigned short*)(ws + 58720256);    // 16 MiB, later CTX, X1BF
  unsigned short* FFBF = (unsigned short*)(ws + 75497472);    // 64 MiB
  float* FF2 = (float*)(ws + 142606336);                      // 32 MiB
  unsigned short* VT   = XBF;
  unsigned short* CTX  = VBF;
  unsigned short* X1BF = VBF;
  float* ATTN = (float*)QBF;  // 32 MiB spanning QBF+KBF
  float* X1   = ATTN;         // LN1 in-place

  // x -> bf16
  k_cvt<<<8192, 256, 0, stream>>>(x, XBF, (B_ * S_ * H_) / 4);
  // QKV projections (Q pre-scaled 1/8)
  k_wtrans<<<dim3(16, 16), 256, 0, stream>>>(Wq, WT, H_, H_);
  k_gemm_bt<1><<<dim3(8, 64), 256, 0, stream>>>(XBF, WT, bq, nullptr, QBF, B_ * S_, H_, H_);
  k_wtrans<<<dim3(16, 16), 256, 0, stream>>>(Wk, WT, H_, H_);
  k_gemm_bt<0><<<dim3(8, 64), 256, 0, stream>>>(XBF, WT, bk, nullptr, KBF, B_ * S_, H_, H_);
  k_wtrans<<<dim3(16, 16), 256, 0, stream>>>(Wv, WT, H_, H_);
  k_gemm_bt<0><<<dim3(8, 64), 256, 0, stream>>>(XBF, WT, bv, nullptr, VBF, B_ * S_, H_, H_);
  // V transpose per head (VT overwrites XBF, which is now dead)
  k_vtrans<<<dim3(32, 64), 256, 0, stream>>>(VBF, VT);
  // fused attention -> CTX (overwrites VBF, dead after vtrans)
  k_attn<<<dim3(32, 64), 256, 0, stream>>>(QBF, KBF, VT, mask, CTX);
  // output projection -> ATTN (f32, overwrites QBF+KBF, dead after attention)
  k_wtrans<<<dim3(16, 16), 256, 0, stream>>>(Wo, WT, H_, H_);
  k_gemm_bt<2><<<dim3(8, 64), 256, 0, stream>>>(CTX, WT, bo, ATTN, nullptr, B_ * S_, H_, H_);
  // LN1: x1 = LN(x + attn_out) (in-place over ATTN) + bf16 copy
  k_ln<1><<<8192, 256, 0, stream>>>(x, ATTN, g1, be1, X1, X1BF);
  // FF1 with gelu -> FFBF
  k_wtrans<<<dim3(16, 64), 256, 0, stream>>>(W1, WT, H_, FF_);
  k_gemm_bt<3><<<dim3(32, 64), 256, 0, stream>>>(X1BF, WT, b1, nullptr, FFBF, B_ * S_, FF_, H_);
  // FF2 -> FF2 (f32)
  k_wtrans<<<dim3(64, 16), 256, 0, stream>>>(W2, WT, FF_, H_);
  k_gemm_bt<2><<<dim3(8, 64), 256, 0, stream>>>(FFBF, WT, b2, FF2, nullptr, B_ * S_, H_, FF_);
  // LN2 -> out
  k_ln<0><<<8192, 256, 0, stream>>>(X1, FF2, g2, be2, out, nullptr);
}

// Round 2
// 782.178 us; speedup vs baseline: 1.3365x; 1.3365x over previous
//
#include <hip/hip_runtime.h>

#define B_ 4
#define S_ 2048
#define H_ 1024
#define NH_ 16
#define HD_ 64
#define FF_ 4096

typedef __attribute__((ext_vector_type(8))) short bfx8;
typedef __attribute__((ext_vector_type(4))) float f32x4;
typedef __attribute__((ext_vector_type(16))) float f32x16;
typedef __attribute__((ext_vector_type(4))) unsigned short us4;

__device__ __forceinline__ unsigned short f2bf(float x) {
  union { float f; unsigned u; } c; c.f = x;
  unsigned r = c.u + 0x7FFFu + ((c.u >> 16) & 1u);
  return (unsigned short)(r >> 16);
}
__device__ __forceinline__ unsigned cvtpk(float a, float b) {
  unsigned r;
  asm("v_cvt_pk_bf16_f32 %0, %1, %2" : "=v"(r) : "v"(a), "v"(b));
  return r;
}
__device__ __forceinline__ f32x4 mfma16(bfx8 a, bfx8 b, f32x4 c) {
  return __builtin_amdgcn_mfma_f32_16x16x32_bf16(a, b, c, 0, 0, 0);
}
__device__ __forceinline__ f32x16 mfma32(bfx8 a, bfx8 b, f32x16 c) {
  return __builtin_amdgcn_mfma_f32_32x32x16_bf16(a, b, c, 0, 0, 0);
}
__device__ __forceinline__ void async16(const unsigned short* g, unsigned short* l) {
  __builtin_amdgcn_global_load_lds(
      (const __attribute__((address_space(1))) unsigned int*)g,
      (__attribute__((address_space(3))) unsigned int*)l, 16, 0, 0);
}
__device__ __forceinline__ float gelu_f(float x) {
  float u = 0.7978845608028654f * (x + 0.044715f * x * x * x);
  float e = __expf(2.f * u);
  float t = 1.f - 2.f / (e + 1.f);
  return 0.5f * x * (1.f + t);
}

// ---------------- fp32 -> bf16 convert ----------------
__global__ __launch_bounds__(256) void k_cvt(const float* __restrict__ in,
                                             unsigned short* __restrict__ out, int n4) {
  int i = blockIdx.x * 256 + threadIdx.x;
  if (i >= n4) return;
  float4 v = ((const float4*)in)[i];
  us4 o; o.x = f2bf(v.x); o.y = f2bf(v.y); o.z = f2bf(v.z); o.w = f2bf(v.w);
  ((us4*)out)[i] = o;
}

// ---------------- concat 3 bias vectors ----------------
__global__ __launch_bounds__(256) void k_cat3(const float* __restrict__ a,
                                              const float* __restrict__ b,
                                              const float* __restrict__ c,
                                              float* __restrict__ o) {
  int i = blockIdx.x * 256 + threadIdx.x;
  if (i >= 3 * H_) return;
  o[i] = i < H_ ? a[i] : (i < 2 * H_ ? b[i - H_] : c[i - 2 * H_]);
}

// ---------------- W [K][N] f32 -> WT [N][K] bf16 ----------------
__global__ __launch_bounds__(256) void k_wtrans(const float* __restrict__ W,
                                                unsigned short* __restrict__ WT,
                                                int K, int N) {
  __shared__ float tile[64][65];
  int k0 = blockIdx.x * 64, n0 = blockIdx.y * 64;
  int t = threadIdx.x;
#pragma unroll
  for (int i = 0; i < 16; i++) {
    int li = t + i * 256;
    int kl = li >> 6, nl = li & 63;
    tile[kl][nl] = W[(size_t)(k0 + kl) * N + n0 + nl];
  }
  __syncthreads();
#pragma unroll
  for (int i = 0; i < 16; i++) {
    int li = t + i * 256;
    int nl = li >> 6, kl = li & 63;
    WT[(size_t)(n0 + nl) * K + k0 + kl] = f2bf(tile[kl][nl]);
  }
}

// ------------- V view [B*S][ld] bf16 -> VT [B*NH][HD][S] bf16 -------------
__global__ __launch_bounds__(256) void k_vtrans(const unsigned short* __restrict__ v,
                                                int ld, unsigned short* __restrict__ vt) {
  __shared__ unsigned short tile[64][65];
  int s0 = blockIdx.x * 64;
  int bh = blockIdx.y;
  int b = bh >> 4, h = bh & 15;
  int t = threadIdx.x;
#pragma unroll
  for (int i = 0; i < 16; i++) {
    int li = t + i * 256;
    int sl = li >> 6, dl = li & 63;
    tile[sl][dl] = v[(size_t)(b * S_ + s0 + sl) * ld + h * HD_ + dl];
  }
  __syncthreads();
#pragma unroll
  for (int i = 0; i < 16; i++) {
    int li = t + i * 256;
    int dl = li >> 6, sl = li & 63;
    vt[((size_t)bh * HD_ + dl) * S_ + s0 + sl] = tile[sl][dl];
  }
}

// ---------------- GEMM: C = A[M][K] @ BT[N][K]^T + bias ----------------
// EPI: 0 = bf16 out, 2 = f32 out, 3 = bf16 gelu
template <int EPI>
__global__ __launch_bounds__(256) void k_gemm_bt(
    const unsigned short* __restrict__ A, const unsigned short* __restrict__ BT,
    const float* __restrict__ bias, float* __restrict__ Cf,
    unsigned short* __restrict__ Cb, int M, int N, int K) {
  __shared__ unsigned short As[128 * 32];
  __shared__ unsigned short Bs[128 * 32];
  const int tid = threadIdx.x;
  const int bx = blockIdx.x, by = blockIdx.y;
  const int wid = tid >> 6, lane = tid & 63;
  const int wr = wid >> 1, wc = wid & 1;
  const int lrow = lane & 15, lk = lane >> 4;

  f32x4 acc[4][4] = {};

  const int arow = tid >> 2, aseg = tid & 3;
  const unsigned short* gA = A + (size_t)(by * 128 + arow) * K + aseg * 8;
  const unsigned short* gB = BT + (size_t)(bx * 128 + arow) * K + aseg * 8;
  unsigned short* lA0 = &As[(tid & ~63) * 8];
  unsigned short* lA1 = lA0 + 2048;
  unsigned short* lB0 = &Bs[(tid & ~63) * 8];
  unsigned short* lB1 = lB0 + 2048;

  for (int k0 = 0; k0 < K; k0 += 32) {
    async16(gA + k0, lA0);
    async16(gA + (size_t)64 * K + k0, lA1);
    async16(gB + k0, lB0);
    async16(gB + (size_t)64 * K + k0, lB1);
    __syncthreads();
    bfx8 af[4], bf[4];
#pragma unroll
    for (int m = 0; m < 4; m++)
      af[m] = *(const bfx8*)&As[(wr * 64 + m * 16 + lrow) * 32 + lk * 8];
#pragma unroll
    for (int n = 0; n < 4; n++)
      bf[n] = *(const bfx8*)&Bs[(wc * 64 + n * 16 + lrow) * 32 + lk * 8];
#pragma unroll
    for (int m = 0; m < 4; m++)
#pragma unroll
      for (int n = 0; n < 4; n++)
        acc[m][n] = mfma16(af[m], bf[n], acc[m][n]);
    __syncthreads();
  }

#pragma unroll
  for (int n = 0; n < 4; n++) {
    const int gcol = bx * 128 + wc * 64 + n * 16 + lrow;
    const float bz = bias[gcol];
#pragma unroll
    for (int m = 0; m < 4; m++) {
      const int gr = by * 128 + wr * 64 + m * 16 + lk * 4;
#pragma unroll
      for (int r = 0; r < 4; r++) {
        float v = acc[m][n][r] + bz;
        if (EPI == 3) v = gelu_f(v);
        size_t idx = (size_t)(gr + r) * N + gcol;
        if (EPI == 2) Cf[idx] = v;
        else Cb[idx] = f2bf(v);
      }
    }
  }
}

// ---------------- fused flash attention, 32x32 MFMA, LDS-free ----------------
// qkv: [B*S][3072] bf16 (Q cols 0..1023, K cols 1024..2047). vt: [B*NH][64][S].
// grid: (S/128, B*NH), 4 waves, wave = 32 q rows. scale 1/8 folded into softmax.
__global__ __launch_bounds__(256) void k_attn(
    const unsigned short* __restrict__ qkv, const unsigned short* __restrict__ vt,
    const float* __restrict__ mask, unsigned short* __restrict__ ctx) {
  const int qb = blockIdx.x, bh = blockIdx.y;
  const int b = bh >> 4, h = bh & 15;
  const int tid = threadIdx.x, wid = tid >> 6, lane = tid & 63;
  const int lq = lane & 31, hi = lane >> 5;
  const int q0 = qb * 128 + wid * 32;
  const int LD = 3 * H_;

  // Q B-fragments (4 d-chunks of 16): Q^T[d][q], lane: q=lq, d=c*16+hi*8+j
  const size_t qrow = ((size_t)b * S_ + q0 + lq) * LD + h * HD_;
  bfx8 qf[4];
#pragma unroll
  for (int c = 0; c < 4; c++) qf[c] = *(const bfx8*)&qkv[qrow + c * 16 + hi * 8];

  float m_run = -1e30f, l_run = 0.f;
  f32x16 o0 = {}, o1 = {};
  const size_t vbase = (size_t)bh * HD_ * S_;
  const float* mrow = mask + (size_t)b * S_;

  for (int kb = 0; kb < S_; kb += 64) {
    // ---- QK^T: S^T[key][q], two 32-key tiles ----
    const size_t kr0 = ((size_t)b * S_ + kb + lq) * LD + H_ + h * HD_;
    bfx8 kf0[4], kf1[4];
#pragma unroll
    for (int c = 0; c < 4; c++) {
      kf0[c] = *(const bfx8*)&qkv[kr0 + c * 16 + hi * 8];
      kf1[c] = *(const bfx8*)&qkv[kr0 + (size_t)32 * LD + c * 16 + hi * 8];
    }
    f32x16 s0 = {}, s1 = {};
    __builtin_amdgcn_s_setprio(1);
#pragma unroll
    for (int c = 0; c < 4; c++) s0 = mfma32(kf0[c], qf[c], s0);
#pragma unroll
    for (int c = 0; c < 4; c++) s1 = mfma32(kf1[c], qf[c], s1);
    __builtin_amdgcn_s_setprio(0);

    // ---- scale + mask: row key = (r&3)+8*(r>>2)+4*hi ----
#pragma unroll
    for (int g = 0; g < 4; g++) {
      const f32x4 m0 = *(const f32x4*)&mrow[kb + g * 8 + hi * 4];
      const f32x4 m1 = *(const f32x4*)&mrow[kb + 32 + g * 8 + hi * 4];
#pragma unroll
      for (int i = 0; i < 4; i++) {
        s0[g * 4 + i] = s0[g * 4 + i] * 0.125f + m0[i];
        s1[g * 4 + i] = s1[g * 4 + i] * 0.125f + m1[i];
      }
    }
    // ---- online softmax (per lane: 32 of the 64 keys; partner has rest) ----
    float mx = s0[0];
#pragma unroll
    for (int r = 1; r < 16; r++) mx = fmaxf(mx, s0[r]);
#pragma unroll
    for (int r = 0; r < 16; r++) mx = fmaxf(mx, s1[r]);
    mx = fmaxf(mx, __shfl_xor(mx, 32));
    const float m_new = fmaxf(m_run, mx);
    const float scale = __expf(m_run - m_new);
    float ps = 0.f;
#pragma unroll
    for (int r = 0; r < 16; r++) { s0[r] = __expf(s0[r] - m_new); ps += s0[r]; }
#pragma unroll
    for (int r = 0; r < 16; r++) { s1[r] = __expf(s1[r] - m_new); ps += s1[r]; }
    ps += __shfl_xor(ps, 32);
    l_run = l_run * scale + ps;
    m_run = m_new;
#pragma unroll
    for (int r = 0; r < 16; r++) { o0[r] *= scale; o1[r] *= scale; }

    // ---- P -> bf16 B-fragments via cvt_pk + half-swap ----
    // own keys (per 32-tile): {0..3,8..11,16..19,24..27}+4*hi
    unsigned t0A0 = cvtpk(s0[0], s0[1]), t0A1 = cvtpk(s0[2], s0[3]);
    unsigned t0B0 = cvtpk(s0[4], s0[5]), t0B1 = cvtpk(s0[6], s0[7]);
    unsigned t0C0 = cvtpk(s0[8], s0[9]), t0C1 = cvtpk(s0[10], s0[11]);
    unsigned t0D0 = cvtpk(s0[12], s0[13]), t0D1 = cvtpk(s0[14], s0[15]);
    unsigned t1A0 = cvtpk(s1[0], s1[1]), t1A1 = cvtpk(s1[2], s1[3]);
    unsigned t1B0 = cvtpk(s1[4], s1[5]), t1B1 = cvtpk(s1[6], s1[7]);
    unsigned t1C0 = cvtpk(s1[8], s1[9]), t1C1 = cvtpk(s1[10], s1[11]);
    unsigned t1D0 = cvtpk(s1[12], s1[13]), t1D1 = cvtpk(s1[14], s1[15]);
    unsigned x0 = __shfl_xor(hi ? t0A0 : t0B0, 32);
    unsigned x1 = __shfl_xor(hi ? t0A1 : t0B1, 32);
    unsigned x2 = __shfl_xor(hi ? t0C0 : t0D0, 32);
    unsigned x3 = __shfl_xor(hi ? t0C1 : t0D1, 32);
    unsigned x4 = __shfl_xor(hi ? t1A0 : t1B0, 32);
    unsigned x5 = __shfl_xor(hi ? t1A1 : t1B1, 32);
    unsigned x6 = __shfl_xor(hi ? t1C0 : t1D0, 32);
    unsigned x7 = __shfl_xor(hi ? t1C1 : t1D1, 32);
    union { unsigned u[4]; bfx8 v; } p00, p01, p10, p11;
    p00.u[0] = hi ? x0 : t0A0;  p00.u[1] = hi ? x1 : t0A1;
    p00.u[2] = hi ? t0B0 : x0;  p00.u[3] = hi ? t0B1 : x1;
    p01.u[0] = hi ? x2 : t0C0;  p01.u[1] = hi ? x3 : t0C1;
    p01.u[2] = hi ? t0D0 : x2;  p01.u[3] = hi ? t0D1 : x3;
    p10.u[0] = hi ? x4 : t1A0;  p10.u[1] = hi ? x5 : t1A1;
    p10.u[2] = hi ? t1B0 : x4;  p10.u[3] = hi ? t1B1 : x5;
    p11.u[0] = hi ? x6 : t1C0;  p11.u[1] = hi ? x7 : t1C1;
    p11.u[2] = hi ? t1D0 : x6;  p11.u[3] = hi ? t1D1 : x7;

    // ---- PV: O^T[d][q] += V^T[d][k] P^T[k][q] ----
    const size_t vr0 = vbase + (size_t)lq * S_ + kb + hi * 8;
    const size_t vr1 = vr0 + (size_t)32 * S_;
    bfx8 v00 = *(const bfx8*)&vt[vr0];
    bfx8 v01 = *(const bfx8*)&vt[vr0 + 16];
    bfx8 v02 = *(const bfx8*)&vt[vr0 + 32];
    bfx8 v03 = *(const bfx8*)&vt[vr0 + 48];
    bfx8 v10 = *(const bfx8*)&vt[vr1];
    bfx8 v11 = *(const bfx8*)&vt[vr1 + 16];
    bfx8 v12 = *(const bfx8*)&vt[vr1 + 32];
    bfx8 v13 = *(const bfx8*)&vt[vr1 + 48];
    __builtin_amdgcn_s_setprio(1);
    o0 = mfma32(v00, p00.v, o0);
    o0 = mfma32(v01, p01.v, o0);
    o0 = mfma32(v02, p10.v, o0);
    o0 = mfma32(v03, p11.v, o0);
    o1 = mfma32(v10, p00.v, o1);
    o1 = mfma32(v11, p01.v, o1);
    o1 = mfma32(v12, p10.v, o1);
    o1 = mfma32(v13, p11.v, o1);
    __builtin_amdgcn_s_setprio(0);
  }

  const float inv = 1.f / l_run;
  unsigned short* crow = ctx + ((size_t)b * S_ + q0 + lq) * H_ + h * HD_;
#pragma unroll
  for (int g = 0; g < 4; g++) {
    us4 w0, w1;
#pragma unroll
    for (int i = 0; i < 4; i++) {
      w0[i] = f2bf(o0[g * 4 + i] * inv);
      w1[i] = f2bf(o1[g * 4 + i] * inv);
    }
    *(us4*)&crow[g * 8 + hi * 4] = w0;
    *(us4*)&crow[32 + g * 8 + hi * 4] = w1;
  }
}

// ---------------- residual + layernorm ----------------
template <int WB>
__global__ __launch_bounds__(256) void k_ln(
    const float* __restrict__ xa, const float* __restrict__ xb,
    const float* __restrict__ g, const float* __restrict__ bt,
    float* __restrict__ outf, unsigned short* __restrict__ outb) {
  const int row = blockIdx.x;
  const int t = threadIdx.x;
  const size_t off = (size_t)row * H_ + t * 4;
  float4 va = *(const float4*)(xa + off);
  float4 vb = *(const float4*)(xb + off);
  float v0 = va.x + vb.x, v1 = va.y + vb.y, v2 = va.z + vb.z, v3 = va.w + vb.w;
  float s = (v0 + v1) + (v2 + v3);
#pragma unroll
  for (int d = 1; d < 64; d <<= 1) s += __shfl_xor(s, d);
  __shared__ float red1[4], red2[4];
  const int wid = t >> 6, lane = t & 63;
  if (lane == 0) red1[wid] = s;
  __syncthreads();
  const float mean = (red1[0] + red1[1] + red1[2] + red1[3]) * (1.f / H_);
  float d0 = v0 - mean, d1 = v1 - mean, d2 = v2 - mean, d3 = v3 - mean;
  float ss = (d0 * d0 + d1 * d1) + (d2 * d2 + d3 * d3);
#pragma unroll
  for (int d = 1; d < 64; d <<= 1) ss += __shfl_xor(ss, d);
  if (lane == 0) red2[wid] = ss;
  __syncthreads();
  const float var = (red2[0] + red2[1] + red2[2] + red2[3]) * (1.f / H_);
  const float rstd = rsqrtf(var + 1e-12f);
  const float4 gv = *(const float4*)(g + t * 4);
  const float4 bv = *(const float4*)(bt + t * 4);
  float y0 = d0 * rstd * gv.x + bv.x;
  float y1 = d1 * rstd * gv.y + bv.y;
  float y2 = d2 * rstd * gv.z + bv.z;
  float y3 = d3 * rstd * gv.w + bv.w;
  float4 yo; yo.x = y0; yo.y = y1; yo.z = y2; yo.w = y3;
  *(float4*)(outf + off) = yo;
  if (WB) {
    us4 ob; ob.x = f2bf(y0); ob.y = f2bf(y1); ob.z = f2bf(y2); ob.w = f2bf(y3);
    *(us4*)(outb + off) = ob;
  }
}

extern "C" void kernel_launch(void* const* d_in, const int* in_sizes, int n_in,
                              void* d_out, int out_size, void* d_ws, size_t ws_size,
                              hipStream_t stream) {
  const float* x    = (const float*)d_in[0];
  const float* mask = (const float*)d_in[1];
  const float* Wq = (const float*)d_in[2];
  const float* bq = (const float*)d_in[3];
  const float* Wk = (const float*)d_in[4];
  const float* bk = (const float*)d_in[5];
  const float* Wv = (const float*)d_in[6];
  const float* bv = (const float*)d_in[7];
  const float* Wo = (const float*)d_in[8];
  const float* bo = (const float*)d_in[9];
  const float* g1  = (const float*)d_in[10];
  const float* be1 = (const float*)d_in[11];
  const float* W1 = (const float*)d_in[12];
  const float* b1 = (const float*)d_in[13];
  const float* W2 = (const float*)d_in[14];
  const float* b2 = (const float*)d_in[15];
  const float* g2  = (const float*)d_in[16];
  const float* be2 = (const float*)d_in[17];
  float* out = (float*)d_out;

  char* ws = (char*)d_ws;
  unsigned short* WT   = (unsigned short*)(ws + 0);          // 8 MiB (W1T max)
  unsigned short* XBF  = (unsigned short*)(ws + 8388608);    // 16 MiB; later X1BF
  unsigned short* QKV  = (unsigned short*)(ws + 25165824);   // 48 MiB [8192][3072]
  unsigned short* VT   = (unsigned short*)(ws + 75497472);   // 16 MiB
  unsigned short* FFBF = (unsigned short*)(ws + 92274688);   // 64 MiB
  unsigned short* CTX  = (unsigned short*)(ws + 159383552);  // 16 MiB
  float* BIAS3 = (float*)CTX;                 // 12 KiB, dead before CTX written
  float* ATTN  = (float*)QKV;                 // 32 MiB, QKV dead after attn
  float* X1    = ATTN;                        // LN1 in-place
  unsigned short* X1BF = XBF;                 // XBF dead after QKV GEMM
  float* FF2   = (float*)(ws + 58720256);     // 32 MiB (over dead QKV tail + VT)

  // x -> bf16; bias concat
  k_cvt<<<8192, 256, 0, stream>>>(x, XBF, (B_ * S_ * H_) / 4);
  k_cat3<<<12, 256, 0, stream>>>(bq, bk, bv, BIAS3);
  // fused QKV projection: [8192][3072]
  k_wtrans<<<dim3(16, 16), 256, 0, stream>>>(Wq, WT, H_, H_);
  k_wtrans<<<dim3(16, 16), 256, 0, stream>>>(Wk, WT + (size_t)1024 * H_, H_, H_);
  k_wtrans<<<dim3(16, 16), 256, 0, stream>>>(Wv, WT + (size_t)2048 * H_, H_, H_);
  k_gemm_bt<0><<<dim3(24, 64), 256, 0, stream>>>(XBF, WT, BIAS3, nullptr, QKV,
                                                 B_ * S_, 3 * H_, H_);
  // V transpose per head
  k_vtrans<<<dim3(32, 64), 256, 0, stream>>>(QKV + 2048, 3 * H_, VT);
  // fused attention -> CTX
  k_attn<<<dim3(16, 64), 256, 0, stream>>>(QKV, VT, mask, CTX);
  // output projection -> ATTN (f32)
  k_wtrans<<<dim3(16, 16), 256, 0, stream>>>(Wo, WT, H_, H_);
  k_gemm_bt<2><<<dim3(8, 64), 256, 0, stream>>>(CTX, WT, bo, ATTN, nullptr,
                                                B_ * S_, H_, H_);
  // LN1 (in-place over ATTN) + bf16 copy
  k_ln<1><<<8192, 256, 0, stream>>>(x, ATTN, g1, be1, X1, X1BF);
  // FF1 + gelu -> FFBF
  k_wtrans<<<dim3(16, 64), 256, 0, stream>>>(W1, WT, H_, FF_);
  k_gemm_bt<3><<<dim3(32, 64), 256, 0, stream>>>(X1BF, WT, b1, nullptr, FFBF,
                                                 B_ * S_, FF_, H_);
  // FF2 -> f32
  k_wtrans<<<dim3(64, 16), 256, 0, stream>>>(W2, WT, FF_, H_);
  k_gemm_bt<2><<<dim3(8, 64), 256, 0, stream>>>(FFBF, WT, b2, FF2, nullptr,
                                                B_ * S_, H_, FF_);
  // LN2 -> out
  k_ln<0><<<8192, 256, 0, stream>>>(X1, FF2, g2, be2, out, nullptr);
}

// Round 3
// 675.902 us; speedup vs baseline: 1.5466x; 1.1572x over previous
//
#include <hip/hip_runtime.h>

#define B_ 4
#define S_ 2048
#define H_ 1024
#define NH_ 16
#define HD_ 64
#define FF_ 4096

typedef __attribute__((ext_vector_type(8))) short bfx8;
typedef __attribute__((ext_vector_type(4))) float f32x4;
typedef __attribute__((ext_vector_type(16))) float f32x16;
typedef __attribute__((ext_vector_type(4))) unsigned short us4;

__device__ __forceinline__ unsigned short f2bf(float x) {
  union { float f; unsigned u; } c; c.f = x;
  unsigned r = c.u + 0x7FFFu + ((c.u >> 16) & 1u);
  return (unsigned short)(r >> 16);
}
__device__ __forceinline__ unsigned cvtpk(float a, float b) {
  unsigned r;
  asm("v_cvt_pk_bf16_f32 %0, %1, %2" : "=v"(r) : "v"(a), "v"(b));
  return r;
}
__device__ __forceinline__ f32x4 mfma16(bfx8 a, bfx8 b, f32x4 c) {
  return __builtin_amdgcn_mfma_f32_16x16x32_bf16(a, b, c, 0, 0, 0);
}
__device__ __forceinline__ f32x16 mfma32(bfx8 a, bfx8 b, f32x16 c) {
  return __builtin_amdgcn_mfma_f32_32x32x16_bf16(a, b, c, 0, 0, 0);
}
__device__ __forceinline__ void async16(const unsigned short* g, unsigned short* l) {
  __builtin_amdgcn_global_load_lds(
      (const __attribute__((address_space(1))) unsigned int*)g,
      (__attribute__((address_space(3))) unsigned int*)l, 16, 0, 0);
}
__device__ __forceinline__ float gelu_f(float x) {
  float u = 0.7978845608028654f * (x + 0.044715f * x * x * x);
  float e = __expf(2.f * u);
  float t = 1.f - 2.f / (e + 1.f);
  return 0.5f * x * (1.f + t);
}

// ---------------- fp32 -> bf16 convert ----------------
__global__ __launch_bounds__(256) void k_cvt(const float* __restrict__ in,
                                             unsigned short* __restrict__ out, int n4) {
  int i = blockIdx.x * 256 + threadIdx.x;
  if (i >= n4) return;
  float4 v = ((const float4*)in)[i];
  us4 o; o.x = f2bf(v.x); o.y = f2bf(v.y); o.z = f2bf(v.z); o.w = f2bf(v.w);
  ((us4*)out)[i] = o;
}

// ---------------- concat 3 bias vectors ----------------
__global__ __launch_bounds__(256) void k_cat3(const float* __restrict__ a,
                                              const float* __restrict__ b,
                                              const float* __restrict__ c,
                                              float* __restrict__ o) {
  int i = blockIdx.x * 256 + threadIdx.x;
  if (i >= 3 * H_) return;
  o[i] = i < H_ ? a[i] : (i < 2 * H_ ? b[i - H_] : c[i - 2 * H_]);
}

// ---------------- W [K][N] f32 -> WT [N][K] bf16 ----------------
__global__ __launch_bounds__(256) void k_wtrans(const float* __restrict__ W,
                                                unsigned short* __restrict__ WT,
                                                int K, int N) {
  __shared__ float tile[64][65];
  int k0 = blockIdx.x * 64, n0 = blockIdx.y * 64;
  int t = threadIdx.x;
#pragma unroll
  for (int i = 0; i < 16; i++) {
    int li = t + i * 256;
    int kl = li >> 6, nl = li & 63;
    tile[kl][nl] = W[(size_t)(k0 + kl) * N + n0 + nl];
  }
  __syncthreads();
#pragma unroll
  for (int i = 0; i < 16; i++) {
    int li = t + i * 256;
    int nl = li >> 6, kl = li & 63;
    WT[(size_t)(n0 + nl) * K + k0 + kl] = f2bf(tile[kl][nl]);
  }
}

// ------------- V view [B*S][ld] bf16 -> VT [B*NH][HD][S] bf16 -------------
__global__ __launch_bounds__(256) void k_vtrans(const unsigned short* __restrict__ v,
                                                int ld, unsigned short* __restrict__ vt) {
  __shared__ unsigned short tile[64][65];
  int s0 = blockIdx.x * 64;
  int bh = blockIdx.y;
  int b = bh >> 4, h = bh & 15;
  int t = threadIdx.x;
#pragma unroll
  for (int i = 0; i < 16; i++) {
    int li = t + i * 256;
    int sl = li >> 6, dl = li & 63;
    tile[sl][dl] = v[(size_t)(b * S_ + s0 + sl) * ld + h * HD_ + dl];
  }
  __syncthreads();
#pragma unroll
  for (int i = 0; i < 16; i++) {
    int li = t + i * 256;
    int dl = li >> 6, sl = li & 63;
    vt[((size_t)bh * HD_ + dl) * S_ + s0 + sl] = tile[sl][dl];
  }
}

// ---------------- GEMM: C = A[M][K] @ BT[N][K]^T + bias ----------------
// EPI: 0 = bf16 out, 2 = f32 out, 3 = bf16 gelu
template <int EPI>
__global__ __launch_bounds__(256) void k_gemm_bt(
    const unsigned short* __restrict__ A, const unsigned short* __restrict__ BT,
    const float* __restrict__ bias, float* __restrict__ Cf,
    unsigned short* __restrict__ Cb, int M, int N, int K) {
  __shared__ unsigned short As[128 * 32];
  __shared__ unsigned short Bs[128 * 32];
  const int tid = threadIdx.x;
  const int bx = blockIdx.x, by = blockIdx.y;
  const int wid = tid >> 6, lane = tid & 63;
  const int wr = wid >> 1, wc = wid & 1;
  const int lrow = lane & 15, lk = lane >> 4;

  f32x4 acc[4][4] = {};

  const int arow = tid >> 2, aseg = tid & 3;
  const unsigned short* gA = A + (size_t)(by * 128 + arow) * K + aseg * 8;
  const unsigned short* gB = BT + (size_t)(bx * 128 + arow) * K + aseg * 8;
  unsigned short* lA0 = &As[(tid & ~63) * 8];
  unsigned short* lA1 = lA0 + 2048;
  unsigned short* lB0 = &Bs[(tid & ~63) * 8];
  unsigned short* lB1 = lB0 + 2048;

  for (int k0 = 0; k0 < K; k0 += 32) {
    async16(gA + k0, lA0);
    async16(gA + (size_t)64 * K + k0, lA1);
    async16(gB + k0, lB0);
    async16(gB + (size_t)64 * K + k0, lB1);
    __syncthreads();
    bfx8 af[4], bf[4];
#pragma unroll
    for (int m = 0; m < 4; m++)
      af[m] = *(const bfx8*)&As[(wr * 64 + m * 16 + lrow) * 32 + lk * 8];
#pragma unroll
    for (int n = 0; n < 4; n++)
      bf[n] = *(const bfx8*)&Bs[(wc * 64 + n * 16 + lrow) * 32 + lk * 8];
#pragma unroll
    for (int m = 0; m < 4; m++)
#pragma unroll
      for (int n = 0; n < 4; n++)
        acc[m][n] = mfma16(af[m], bf[n], acc[m][n]);
    __syncthreads();
  }

#pragma unroll
  for (int n = 0; n < 4; n++) {
    const int gcol = bx * 128 + wc * 64 + n * 16 + lrow;
    const float bz = bias[gcol];
#pragma unroll
    for (int m = 0; m < 4; m++) {
      const int gr = by * 128 + wr * 64 + m * 16 + lk * 4;
#pragma unroll
      for (int r = 0; r < 4; r++) {
        float v = acc[m][n][r] + bz;
        if (EPI == 3) v = gelu_f(v);
        size_t idx = (size_t)(gr + r) * N + gcol;
        if (EPI == 2) Cf[idx] = v;
        else Cb[idx] = f2bf(v);
      }
    }
  }
}

// ------- fused flash attention, 32x32 MFMA, LDS-staged fragment tiles -------
// qkv: [B*S][3072] bf16 (K at col 1024). vt: [B*NH][64][S].
// grid: 1024 blocks 1D (XCD-chunk swizzled), 4 waves, wave = 32 q rows.
// LDS per 64-key tile (16KB): K frags [t32][c][lane] then V frags [ks][db][lane],
// staged via global_load_lds with per-lane fragment-source addresses.
__global__ __launch_bounds__(256) void k_attn(
    const unsigned short* __restrict__ qkv, const unsigned short* __restrict__ vt,
    const float* __restrict__ mask, unsigned short* __restrict__ ctx) {
  __shared__ unsigned short lds[2][8192];
  const int id = blockIdx.x;
  const int jj = (id & 7) * 128 + (id >> 3);  // XCD-chunk: 8 heads per XCD
  const int bh = jj >> 4, qb = jj & 15;
  const int b = bh >> 4, h = bh & 15;
  const int tid = threadIdx.x, wid = tid >> 6, lane = tid & 63;
  const int lq = lane & 31, hi = lane >> 5;
  const int q0 = qb * 128 + wid * 32;
  const int LD = 3 * H_;
  const int NT = S_ / 64;

  // per-thread staging source bases (chunk f = j*256+tid; c=tid>>6, l=tid&63)
  const size_t KC = ((size_t)b * S_ + (tid & 31)) * LD + H_ + h * HD_ +
                    (tid >> 6) * 16 + ((tid >> 5) & 1) * 8;
  const size_t VC = ((size_t)bh * HD_ + ((tid >> 6) & 1) * 32 + (tid & 31)) * S_ +
                    (tid >> 7) * 16 + ((tid >> 5) & 1) * 8;

  // Q B-fragments: lane q=lq, d = c*16 + hi*8 + j
  const size_t qrow = ((size_t)b * S_ + q0 + lq) * LD + h * HD_;
  bfx8 qf[4];
#pragma unroll
  for (int c = 0; c < 4; c++) qf[c] = *(const bfx8*)&qkv[qrow + c * 16 + hi * 8];

  // prologue: stage tile 0
  {
    unsigned short* lb = &lds[0][wid * 512];
    async16(qkv + KC, lb);
    async16(qkv + KC + (size_t)32 * LD, lb + 2048);
    async16(vt + VC, lb + 4096);
    async16(vt + VC + 32, lb + 6144);
  }
  asm volatile("s_waitcnt vmcnt(0)" ::: "memory");
  __syncthreads();

  float m_run = -1e30f, l_run = 0.f;
  f32x16 o0 = {}, o1 = {};
  const float* mrow = mask + (size_t)b * S_;

  for (int t = 0; t < NT; t++) {
    const int bb = t & 1;
    if (t + 1 < NT) {  // stage next tile into other buffer
      unsigned short* lb = &lds[bb ^ 1][wid * 512];
      const size_t ko = KC + (size_t)((t + 1) * 64) * LD;
      const size_t vo = VC + (size_t)(t + 1) * 64;
      async16(qkv + ko, lb);
      async16(qkv + ko + (size_t)32 * LD, lb + 2048);
      async16(vt + vo, lb + 4096);
      async16(vt + vo + 32, lb + 6144);
    }
    const unsigned short* L = lds[bb];

    // ---- QK^T ----
    bfx8 kf0[4], kf1[4];
#pragma unroll
    for (int c = 0; c < 4; c++) {
      kf0[c] = *(const bfx8*)&L[(c * 64 + lane) * 8];
      kf1[c] = *(const bfx8*)&L[((4 + c) * 64 + lane) * 8];
    }
    f32x16 s0 = {}, s1 = {};
    __builtin_amdgcn_s_setprio(1);
#pragma unroll
    for (int c = 0; c < 4; c++) s0 = mfma32(kf0[c], qf[c], s0);
#pragma unroll
    for (int c = 0; c < 4; c++) s1 = mfma32(kf1[c], qf[c], s1);
    __builtin_amdgcn_s_setprio(0);

    // ---- scale + mask ----
    const int kb = t * 64;
#pragma unroll
    for (int g = 0; g < 4; g++) {
      const f32x4 m0 = *(const f32x4*)&mrow[kb + g * 8 + hi * 4];
      const f32x4 m1 = *(const f32x4*)&mrow[kb + 32 + g * 8 + hi * 4];
#pragma unroll
      for (int i = 0; i < 4; i++) {
        s0[g * 4 + i] = s0[g * 4 + i] * 0.125f + m0[i];
        s1[g * 4 + i] = s1[g * 4 + i] * 0.125f + m1[i];
      }
    }
    // ---- online softmax with defer-max (THR=8) ----
    float mx = s0[0];
#pragma unroll
    for (int r = 1; r < 16; r++) mx = fmaxf(mx, s0[r]);
#pragma unroll
    for (int r = 0; r < 16; r++) mx = fmaxf(mx, s1[r]);
    mx = fmaxf(mx, __shfl_xor(mx, 32));
    if (!__all(mx <= m_run + 8.f)) {
      const float m_new = fmaxf(m_run, mx);
      const float scale = __expf(m_run - m_new);
      l_run *= scale;
#pragma unroll
      for (int r = 0; r < 16; r++) { o0[r] *= scale; o1[r] *= scale; }
      m_run = m_new;
    }
    float ps = 0.f;
#pragma unroll
    for (int r = 0; r < 16; r++) { s0[r] = __expf(s0[r] - m_run); ps += s0[r]; }
#pragma unroll
    for (int r = 0; r < 16; r++) { s1[r] = __expf(s1[r] - m_run); ps += s1[r]; }
    ps += __shfl_xor(ps, 32);
    l_run += ps;

    // ---- P -> bf16 B-fragments via cvt_pk + half-swap ----
    unsigned t0A0 = cvtpk(s0[0], s0[1]), t0A1 = cvtpk(s0[2], s0[3]);
    unsigned t0B0 = cvtpk(s0[4], s0[5]), t0B1 = cvtpk(s0[6], s0[7]);
    unsigned t0C0 = cvtpk(s0[8], s0[9]), t0C1 = cvtpk(s0[10], s0[11]);
    unsigned t0D0 = cvtpk(s0[12], s0[13]), t0D1 = cvtpk(s0[14], s0[15]);
    unsigned t1A0 = cvtpk(s1[0], s1[1]), t1A1 = cvtpk(s1[2], s1[3]);
    unsigned t1B0 = cvtpk(s1[4], s1[5]), t1B1 = cvtpk(s1[6], s1[7]);
    unsigned t1C0 = cvtpk(s1[8], s1[9]), t1C1 = cvtpk(s1[10], s1[11]);
    unsigned t1D0 = cvtpk(s1[12], s1[13]), t1D1 = cvtpk(s1[14], s1[15]);
    unsigned x0 = __shfl_xor(hi ? t0A0 : t0B0, 32);
    unsigned x1 = __shfl_xor(hi ? t0A1 : t0B1, 32);
    unsigned x2 = __shfl_xor(hi ? t0C0 : t0D0, 32);
    unsigned x3 = __shfl_xor(hi ? t0C1 : t0D1, 32);
    unsigned x4 = __shfl_xor(hi ? t1A0 : t1B0, 32);
    unsigned x5 = __shfl_xor(hi ? t1A1 : t1B1, 32);
    unsigned x6 = __shfl_xor(hi ? t1C0 : t1D0, 32);
    unsigned x7 = __shfl_xor(hi ? t1C1 : t1D1, 32);
    union { unsigned u[4]; bfx8 v; } p00, p01, p10, p11;
    p00.u[0] = hi ? x0 : t0A0;  p00.u[1] = hi ? x1 : t0A1;
    p00.u[2] = hi ? t0B0 : x0;  p00.u[3] = hi ? t0B1 : x1;
    p01.u[0] = hi ? x2 : t0C0;  p01.u[1] = hi ? x3 : t0C1;
    p01.u[2] = hi ? t0D0 : x2;  p01.u[3] = hi ? t0D1 : x3;
    p10.u[0] = hi ? x4 : t1A0;  p10.u[1] = hi ? x5 : t1A1;
    p10.u[2] = hi ? t1B0 : x4;  p10.u[3] = hi ? t1B1 : x5;
    p11.u[0] = hi ? x6 : t1C0;  p11.u[1] = hi ? x7 : t1C1;
    p11.u[2] = hi ? t1D0 : x6;  p11.u[3] = hi ? t1D1 : x7;

    // ---- PV ----
    bfx8 v00 = *(const bfx8*)&L[4096 + (0 * 64 + lane) * 8];
    bfx8 v10 = *(const bfx8*)&L[4096 + (1 * 64 + lane) * 8];
    bfx8 v01 = *(const bfx8*)&L[4096 + (2 * 64 + lane) * 8];
    bfx8 v11 = *(const bfx8*)&L[4096 + (3 * 64 + lane) * 8];
    bfx8 v02 = *(const bfx8*)&L[4096 + (4 * 64 + lane) * 8];
    bfx8 v12 = *(const bfx8*)&L[4096 + (5 * 64 + lane) * 8];
    bfx8 v03 = *(const bfx8*)&L[4096 + (6 * 64 + lane) * 8];
    bfx8 v13 = *(const bfx8*)&L[4096 + (7 * 64 + lane) * 8];
    __builtin_amdgcn_s_setprio(1);
    o0 = mfma32(v00, p00.v, o0);
    o0 = mfma32(v01, p01.v, o0);
    o0 = mfma32(v02, p10.v, o0);
    o0 = mfma32(v03, p11.v, o0);
    o1 = mfma32(v10, p00.v, o1);
    o1 = mfma32(v11, p01.v, o1);
    o1 = mfma32(v12, p10.v, o1);
    o1 = mfma32(v13, p11.v, o1);
    __builtin_amdgcn_s_setprio(0);

    asm volatile("s_waitcnt vmcnt(0)" ::: "memory");
    __syncthreads();
  }

  const float inv = 1.f / l_run;
  unsigned short* crow = ctx + ((size_t)b * S_ + q0 + lq) * H_ + h * HD_;
#pragma unroll
  for (int g = 0; g < 4; g++) {
    us4 w0, w1;
#pragma unroll
    for (int i = 0; i < 4; i++) {
      w0[i] = f2bf(o0[g * 4 + i] * inv);
      w1[i] = f2bf(o1[g * 4 + i] * inv);
    }
    *(us4*)&crow[g * 8 + hi * 4] = w0;
    *(us4*)&crow[32 + g * 8 + hi * 4] = w1;
  }
}

// ---------------- residual + layernorm ----------------
template <int WB>
__global__ __launch_bounds__(256) void k_ln(
    const float* __restrict__ xa, const float* __restrict__ xb,
    const float* __restrict__ g, const float* __restrict__ bt,
    float* __restrict__ outf, unsigned short* __restrict__ outb) {
  const int row = blockIdx.x;
  const int t = threadIdx.x;
  const size_t off = (size_t)row * H_ + t * 4;
  float4 va = *(const float4*)(xa + off);
  float4 vb = *(const float4*)(xb + off);
  float v0 = va.x + vb.x, v1 = va.y + vb.y, v2 = va.z + vb.z, v3 = va.w + vb.w;
  float s = (v0 + v1) + (v2 + v3);
#pragma unroll
  for (int d = 1; d < 64; d <<= 1) s += __shfl_xor(s, d);
  __shared__ float red1[4], red2[4];
  const int wid = t >> 6, lane = t & 63;
  if (lane == 0) red1[wid] = s;
  __syncthreads();
  const float mean = (red1[0] + red1[1] + red1[2] + red1[3]) * (1.f / H_);
  float d0 = v0 - mean, d1 = v1 - mean, d2 = v2 - mean, d3 = v3 - mean;
  float ss = (d0 * d0 + d1 * d1) + (d2 * d2 + d3 * d3);
#pragma unroll
  for (int d = 1; d < 64; d <<= 1) ss += __shfl_xor(ss, d);
  if (lane == 0) red2[wid] = ss;
  __syncthreads();
  const float var = (red2[0] + red2[1] + red2[2] + red2[3]) * (1.f / H_);
  const float rstd = rsqrtf(var + 1e-12f);
  const float4 gv = *(const float4*)(g + t * 4);
  const float4 bv = *(const float4*)(bt + t * 4);
  float y0 = d0 * rstd * gv.x + bv.x;
  float y1 = d1 * rstd * gv.y + bv.y;
  float y2 = d2 * rstd * gv.z + bv.z;
  float y3 = d3 * rstd * gv.w + bv.w;
  float4 yo; yo.x = y0; yo.y = y1; yo.z = y2; yo.w = y3;
  *(float4*)(outf + off) = yo;
  if (WB) {
    us4 ob; ob.x = f2bf(y0); ob.y = f2bf(y1); ob.z = f2bf(y2); ob.w = f2bf(y3);
    *(us4*)(outb + off) = ob;
  }
}

extern "C" void kernel_launch(void* const* d_in, const int* in_sizes, int n_in,
                              void* d_out, int out_size, void* d_ws, size_t ws_size,
                              hipStream_t stream) {
  const float* x    = (const float*)d_in[0];
  const float* mask = (const float*)d_in[1];
  const float* Wq = (const float*)d_in[2];
  const float* bq = (const float*)d_in[3];
  const float* Wk = (const float*)d_in[4];
  const float* bk = (const float*)d_in[5];
  const float* Wv = (const float*)d_in[6];
  const float* bv = (const float*)d_in[7];
  const float* Wo = (const float*)d_in[8];
  const float* bo = (const float*)d_in[9];
  const float* g1  = (const float*)d_in[10];
  const float* be1 = (const float*)d_in[11];
  const float* W1 = (const float*)d_in[12];
  const float* b1 = (const float*)d_in[13];
  const float* W2 = (const float*)d_in[14];
  const float* b2 = (const float*)d_in[15];
  const float* g2  = (const float*)d_in[16];
  const float* be2 = (const float*)d_in[17];
  float* out = (float*)d_out;

  char* ws = (char*)d_ws;
  unsigned short* WT   = (unsigned short*)(ws + 0);          // 8 MiB (W1T max)
  unsigned short* XBF  = (unsigned short*)(ws + 8388608);    // 16 MiB; later X1BF
  unsigned short* QKV  = (unsigned short*)(ws + 25165824);   // 48 MiB [8192][3072]
  unsigned short* VT   = (unsigned short*)(ws + 75497472);   // 16 MiB
  unsigned short* FFBF = (unsigned short*)(ws + 92274688);   // 64 MiB
  unsigned short* CTX  = (unsigned short*)(ws + 159383552);  // 16 MiB
  float* BIAS3 = (float*)CTX;                 // 12 KiB, dead before CTX written
  float* ATTN  = (float*)QKV;                 // 32 MiB, QKV dead after attn
  float* X1    = ATTN;                        // LN1 in-place
  unsigned short* X1BF = XBF;                 // XBF dead after QKV GEMM
  float* FF2   = (float*)(ws + 58720256);     // 32 MiB (over dead QKV tail + VT)

  // x -> bf16; bias concat
  k_cvt<<<8192, 256, 0, stream>>>(x, XBF, (B_ * S_ * H_) / 4);
  k_cat3<<<12, 256, 0, stream>>>(bq, bk, bv, BIAS3);
  // fused QKV projection: [8192][3072]
  k_wtrans<<<dim3(16, 16), 256, 0, stream>>>(Wq, WT, H_, H_);
  k_wtrans<<<dim3(16, 16), 256, 0, stream>>>(Wk, WT + (size_t)1024 * H_, H_, H_);
  k_wtrans<<<dim3(16, 16), 256, 0, stream>>>(Wv, WT + (size_t)2048 * H_, H_, H_);
  k_gemm_bt<0><<<dim3(24, 64), 256, 0, stream>>>(XBF, WT, BIAS3, nullptr, QKV,
                                                 B_ * S_, 3 * H_, H_);
  // V transpose per head
  k_vtrans<<<dim3(32, 64), 256, 0, stream>>>(QKV + 2048, 3 * H_, VT);
  // fused attention -> CTX
  k_attn<<<1024, 256, 0, stream>>>(QKV, VT, mask, CTX);
  // output projection -> ATTN (f32)
  k_wtrans<<<dim3(16, 16), 256, 0, stream>>>(Wo, WT, H_, H_);
  k_gemm_bt<2><<<dim3(8, 64), 256, 0, stream>>>(CTX, WT, bo, ATTN, nullptr,
                                                B_ * S_, H_, H_);
  // LN1 (in-place over ATTN) + bf16 copy
  k_ln<1><<<8192, 256, 0, stream>>>(x, ATTN, g1, be1, X1, X1BF);
  // FF1 + gelu -> FFBF
  k_wtrans<<<dim3(16, 64), 256, 0, stream>>>(W1, WT, H_, FF_);
  k_gemm_bt<3><<<dim3(32, 64), 256, 0, stream>>>(X1BF, WT, b1, nullptr, FFBF,
                                                 B_ * S_, FF_, H_);
  // FF2 -> f32
  k_wtrans<<<dim3(64, 16), 256, 0, stream>>>(W2, WT, FF_, H_);
  k_gemm_bt<2><<<dim3(8, 64), 256, 0, stream>>>(FFBF, WT, b2, FF2, nullptr,
                                                B_ * S_, H_, FF_);
  // LN2 -> out
  k_ln<0><<<8192, 256, 0, stream>>>(X1, FF2, g2, be2, out, nullptr);
}